// Round 4
// baseline (344.718 us; speedup 1.0000x reference)
//
#include <hip/hip_runtime.h>
#include <stdint.h>

#define NN 512
#define PAIR 128
#define SINGLE 256

#define GAINv 1.5927812698663017f
#define RS2 0.70710678118654752f

typedef unsigned int uint;
typedef unsigned short ushort;
typedef short bf16x8 __attribute__((ext_vector_type(8)));
typedef float f32x4 __attribute__((ext_vector_type(4)));

__device__ __forceinline__ ushort f2b(float f){
  union{float f;uint i;}v; v.f=f;
  uint x=v.i;
  return (ushort)((x + 0x7FFFu + ((x>>16)&1u))>>16);  // RNE, finite inputs only
}
__device__ __forceinline__ float b2f_lo(uint u){ union{uint i;float f;}v; v.i=u<<16; return v.f; }
__device__ __forceinline__ float b2f_hi(uint u){ union{uint i;float f;}v; v.i=u&0xFFFF0000u; return v.f; }
__device__ __forceinline__ float tanh_fast(float x){
  float xc = fminf(fmaxf(x,-8.f),8.f);
  float e = __expf(2.f*xc);
  return (e-1.f)*__builtin_amdgcn_rcpf(e+1.f);
}

// ---------------- k1: g1 spin-partials + W2^T->bf16 + zero g2acc ------------------
__global__ __launch_bounds__(256) void k1_prep(const float* __restrict__ h_one,
                                               const float* __restrict__ w2,
                                               float* __restrict__ g1part,
                                               ushort* __restrict__ wt,
                                               float* __restrict__ g2acc)
{
  const int b = blockIdx.x, t = threadIdx.x;
  if(b < 8){
    const int rb = b*64;
    float s = 0.f;
    for(int i=0;i<64;i++) s += h_one[(size_t)(rb+i)*SINGLE + t];
    g1part[b*SINGLE + t] = s;                    // blocks 0..3 spin0, 4..7 spin1
  } else if(b < 16){
    const int bb = b-8;                          // 16 rows of W2 each
    for(int e=t; e<16*128; e+=256){
      int kl = e>>7, n = e&127;
      int k = bb*16 + kl;
      wt[n*128 + k] = f2b(w2[(size_t)k*128 + n]);  // wt[n][k] = bf16(W2[k][n]), linear
    }
  } else {
    // zero g2acc: 131072 floats = 32768 f32x4, 8 blocks
    f32x4 z = (f32x4){0.f,0.f,0.f,0.f};
    f32x4* dst = (f32x4*)g2acc + (size_t)(b-16)*4096;
    for(int q=t; q<4096; q+=256) dst[q] = z;
  }
}

// ---------------- k2: gterm partials (plain stores, no atomics) -------------------
__global__ __launch_bounds__(256) void k2_gterm(const float* __restrict__ g1part,
                                                const float* __restrict__ wg,
                                                float* __restrict__ gtermpart)
{
  __shared__ float g1m[512];
  const int t = threadIdx.x;
  g1m[t]     = (g1part[t]      + g1part[256+t]  + g1part[512+t]  + g1part[768+t])  * (1.f/256.f);
  g1m[t+256] = (g1part[1024+t] + g1part[1280+t] + g1part[1536+t] + g1part[1792+t]) * (1.f/256.f);
  __syncthreads();
  const int fb = blockIdx.x*64;
  float s = 0.f;
  for(int f=fb; f<fb+64; f++)
    s += g1m[f]*wg[(size_t)f*SINGLE + t];
  gtermpart[blockIdx.x*SINGLE + t] = s;
}

// ---------------- k3: h_two fused GEMM, 4 j-tiles/block, double-buffered ----------
// 1024 blocks (4/CU); block owns rows i0..i0+15, j-tiles j0base..j0base+15.
// Per tile: prefetch next tile's f32 (issued before compute), g2 partial, GEMM
// (W2^T frags register-resident), fused epilogue; one barrier per tile.
// LDS XOR-swizzle (elem ^= (row&7)<<3) keeps ds_read_b128 conflicts at 2-way.
__global__ __launch_bounds__(256, 4) void k3_htwo(
    const float* __restrict__ h_two,
    const float* __restrict__ b2,
    const ushort* __restrict__ wt,
    float* __restrict__ g2acc,
    float* __restrict__ out_h2)
{
  __shared__ __align__(16) ushort At[2][64*128];  // 2 x 16KB bf16, swizzled
  const int tid = threadIdx.x;
  const int w = tid>>6, lane = tid&63;
  const int lq = lane>>4, lr = lane&15;
  const int bi = blockIdx.x & 31;                // 32 row-groups of 16
  const int bjg = blockIdx.x >> 5;               // 32 j-groups of 16
  const int i0 = bi*16;
  const int j0base = bjg*16;
  const int spin = bi>>4;

  // prologue: issue tile-0 loads
  float4 L[8];
  #pragma unroll
  for(int rep=0;rep<8;rep++){
    const int e = rep*1024 + tid*4;
    const int di = e>>9, c = e&511;
    L[rep] = *(const float4*)(h_two + ((size_t)(i0+di)*NN + j0base)*PAIR + c);
  }
  // W2^T fragments + bias (L2-hot), overlap with loads in flight
  bf16x8 af[2][4];
  #pragma unroll
  for(int nt=0;nt<2;nt++){
    const int n = w*32 + nt*16 + lr;
    #pragma unroll
    for(int kk=0;kk<4;kk++)
      af[nt][kk] = *(const bf16x8*)(wt + n*128 + kk*32 + lq*8);
  }
  f32x4 bias[2];
  #pragma unroll
  for(int nt=0;nt<2;nt++){
    const float4 bv = *(const float4*)(b2 + w*32 + nt*16 + lq*4);
    bias[nt] = (f32x4){bv.x, bv.y, bv.z, bv.w};
  }
  // write tile 0 into buf 0
  #pragma unroll
  for(int rep=0;rep<8;rep++){
    const int e = rep*1024 + tid*4;
    const int r = e>>7;
    ushort4 pk; pk.x=f2b(L[rep].x); pk.y=f2b(L[rep].y); pk.z=f2b(L[rep].z); pk.w=f2b(L[rep].w);
    *(ushort4*)(&At[0][e ^ ((r&7)<<3)]) = pk;
  }
  __syncthreads();

  #pragma unroll
  for(int t=0;t<4;t++){
    const int j0 = j0base + t*4;
    const ushort* cur = &At[t&1][0];

    // prefetch next tile (issue loads NOW; consumed after compute)
    if(t<3){
      #pragma unroll
      for(int rep=0;rep<8;rep++){
        const int e = rep*1024 + tid*4;
        const int di = e>>9, c = e&511;
        L[rep] = *(const float4*)(h_two + ((size_t)(i0+di)*NN + (j0+4))*PAIR + c);
      }
    }

    // g2 column sums over the 16 i's (bf16-sourced; error << tolerance)
    {
      const uint* a32 = (const uint*)cur;
      float s0=0.f, s1=0.f;
      #pragma unroll
      for(int di=0;di<16;di++){
        const int r = di*4+w;
        uint u = a32[(r*64 + lane) ^ ((r&7)<<2)];
        s0 += b2f_lo(u); s1 += b2f_hi(u);
      }
      float* dst = g2acc + ((size_t)spin*NN + (j0+w))*PAIR + lane*2;
      atomicAdd(dst, s0); atomicAdd(dst+1, s1);
    }

    // GEMM split by nt (16 acc regs live) with fused per-nt epilogue
    #pragma unroll
    for(int nt=0;nt<2;nt++){
      f32x4 acc[4];
      #pragma unroll
      for(int mt=0;mt<4;mt++) acc[mt] = bias[nt];
      #pragma unroll
      for(int kk=0;kk<4;kk++){
        #pragma unroll
        for(int mt=0;mt<4;mt++){
          const int m = mt*16 + lr;              // (m&7) == (lr&7)
          const int e = m*128 + kk*32 + lq*8;
          const bf16x8 bfr = *(const bf16x8*)(&cur[e ^ ((lr&7)<<3)]);
          acc[mt] = __builtin_amdgcn_mfma_f32_16x16x32_bf16(af[nt][kk], bfr, acc[mt], 0,0,0);
        }
      }
      #pragma unroll
      for(int mt=0;mt<4;mt++){
        const int m = mt*16 + lr;
        const size_t base = ((size_t)(i0 + (m>>2))*NN + (j0 + (m&3)))*PAIR;
        const int nb = w*32 + nt*16 + lq*4;
        const float4 rr = *(const float4*)(h_two + base + nb);
        f32x4 o;
        o[0] = (rr.x + GAINv*tanh_fast(acc[mt][0]))*RS2;
        o[1] = (rr.y + GAINv*tanh_fast(acc[mt][1]))*RS2;
        o[2] = (rr.z + GAINv*tanh_fast(acc[mt][2]))*RS2;
        o[3] = (rr.w + GAINv*tanh_fast(acc[mt][3]))*RS2;
        *(f32x4*)(out_h2 + base + nb) = o;
      }
    }

    // convert + write next tile into other buffer, single barrier per tile
    if(t<3){
      ushort* nxt = &At[(t+1)&1][0];
      #pragma unroll
      for(int rep=0;rep<8;rep++){
        const int e = rep*1024 + tid*4;
        const int r = e>>7;
        ushort4 pk; pk.x=f2b(L[rep].x); pk.y=f2b(L[rep].y); pk.z=f2b(L[rep].z); pk.w=f2b(L[rep].w);
        *(ushort4*)(&nxt[e ^ ((r&7)<<3)]) = pk;
      }
      __syncthreads();
    }
  }
}

// ---------------- k4: h_one path — 1 row/block (512 blocks = 2/CU) ----------------
__global__ __launch_bounds__(256) void k4_hone(
    const float* __restrict__ h_one,
    const float* __restrict__ w1,
    const float* __restrict__ b1,
    const float* __restrict__ g2acc,
    const float* __restrict__ gtermpart,
    float* __restrict__ out_h1)
{
  __shared__ float onein[512];
  const int n   = threadIdx.x;
  const int row = blockIdx.x;
  onein[n] = h_one[(size_t)row*SINGLE + n];
  {
    int sp = n>>7, p = n&127;
    onein[256+n] = g2acc[((size_t)sp*NN + row)*PAIR + p] * (1.f/256.f);
  }
  float gt = 0.f;
  #pragma unroll
  for(int bb=0;bb<8;bb++) gt += gtermpart[bb*256+n];
  __syncthreads();
  float a = 0.f;
  for(int f=0; f<512; f++)
    a += onein[f] * w1[(size_t)f*SINGLE + n];
  float x = (a + b1[n] + gt) * RS2;
  out_h1[(size_t)row*SINGLE + n] = (onein[n] + GAINv*tanh_fast(x)) * RS2;
}

extern "C" void kernel_launch(void* const* d_in, const int* in_sizes, int n_in,
                              void* d_out, int out_size, void* d_ws, size_t ws_size,
                              hipStream_t stream)
{
  const float* h_one = (const float*)d_in[0];
  const float* h_two = (const float*)d_in[1];
  const float* W1    = (const float*)d_in[2];
  const float* b1    = (const float*)d_in[3];
  const float* Wg    = (const float*)d_in[4];
  const float* W2    = (const float*)d_in[5];
  const float* b2    = (const float*)d_in[6];

  float* wsf       = (float*)d_ws;
  float* g2acc     = wsf;                        // [2][512][128] f32 sums (atomic)
  ushort* wt       = (ushort*)(wsf + 131072);    // W2^T bf16 [n][k], linear
  float* g1part    = wsf + 139264;               // [8][256] spin partial sums
  float* gtermpart = wsf + 141312;               // [8][256] gterm partials

  float* out_h1 = (float*)d_out;
  float* out_h2 = out_h1 + 131072;

  k1_prep <<<24,   256, 0, stream>>>(h_one, W2, g1part, wt, g2acc);
  k2_gterm<<<8,    256, 0, stream>>>(g1part, Wg, gtermpart);
  k3_htwo <<<1024, 256, 0, stream>>>(h_two, b2, wt, g2acc, out_h2);
  k4_hone <<<512,  256, 0, stream>>>(h_one, W1, b1, g2acc, gtermpart, out_h1);
}

// Round 5
// 334.556 us; speedup vs baseline: 1.0304x; 1.0304x over previous
//
#include <hip/hip_runtime.h>
#include <stdint.h>

#define NN 512
#define PAIR 128
#define SINGLE 256

#define GAINv 1.5927812698663017f
#define RS2 0.70710678118654752f

typedef unsigned int uint;
typedef unsigned short ushort;
typedef short bf16x8 __attribute__((ext_vector_type(8)));
typedef float f32x4 __attribute__((ext_vector_type(4)));

__device__ __forceinline__ ushort f2b(float f){
  union{float f;uint i;}v; v.f=f;
  uint x=v.i;
  return (ushort)((x + 0x7FFFu + ((x>>16)&1u))>>16);  // RNE, finite inputs only
}
__device__ __forceinline__ float b2f_lo(uint u){ union{uint i;float f;}v; v.i=u<<16; return v.f; }
__device__ __forceinline__ float b2f_hi(uint u){ union{uint i;float f;}v; v.i=u&0xFFFF0000u; return v.f; }
__device__ __forceinline__ float tanh_fast(float x){
  float xc = fminf(fmaxf(x,-8.f),8.f);
  float e = __expf(2.f*xc);
  return (e-1.f)*__builtin_amdgcn_rcpf(e+1.f);
}

// ---------------- k1: g1 spin-partials + W2^T->bf16 + zero g2acc ------------------
__global__ __launch_bounds__(256) void k1_prep(const float* __restrict__ h_one,
                                               const float* __restrict__ w2,
                                               float* __restrict__ g1part,
                                               ushort* __restrict__ wt,
                                               float* __restrict__ g2acc)
{
  const int b = blockIdx.x, t = threadIdx.x;
  if(b < 8){
    const int rb = b*64;
    float s = 0.f;
    for(int i=0;i<64;i++) s += h_one[(size_t)(rb+i)*SINGLE + t];
    g1part[b*SINGLE + t] = s;                    // blocks 0..3 spin0, 4..7 spin1
  } else if(b < 16){
    const int bb = b-8;                          // 16 rows of W2 each
    for(int e=t; e<16*128; e+=256){
      int kl = e>>7, n = e&127;
      int k = bb*16 + kl;
      wt[n*128 + k] = f2b(w2[(size_t)k*128 + n]);  // wt[n][k] = bf16(W2[k][n]), linear
    }
  } else {
    // zero g2acc: 131072 floats = 32768 f32x4, 8 blocks
    f32x4 z = (f32x4){0.f,0.f,0.f,0.f};
    f32x4* dst = (f32x4*)g2acc + (size_t)(b-16)*4096;
    for(int q=t; q<4096; q+=256) dst[q] = z;
  }
}

// ---------------- k2: gterm partials (plain stores, no atomics) -------------------
__global__ __launch_bounds__(256) void k2_gterm(const float* __restrict__ g1part,
                                                const float* __restrict__ wg,
                                                float* __restrict__ gtermpart)
{
  __shared__ float g1m[512];
  const int t = threadIdx.x;
  g1m[t]     = (g1part[t]      + g1part[256+t]  + g1part[512+t]  + g1part[768+t])  * (1.f/256.f);
  g1m[t+256] = (g1part[1024+t] + g1part[1280+t] + g1part[1536+t] + g1part[1792+t]) * (1.f/256.f);
  __syncthreads();
  const int fb = blockIdx.x*64;
  float s = 0.f;
  for(int f=fb; f<fb+64; f++)
    s += g1m[f]*wg[(size_t)f*SINGLE + t];
  gtermpart[blockIdx.x*SINGLE + t] = s;
}

// ---------------- k3: h_two fused GEMM, 16i x 4j tile, swizzled 16KB LDS ----------
// Round-3 structure (best measured), single change: 8 blocks/CU occupancy.
// 4 waves; wave w owns output features n in [w*32, w*32+32), all 64 tile rows.
// W2^T fragments register-resident (from L2). At staged coalesced f32->bf16 into
// XOR-swizzled LDS (elem ^= (row&7)<<3): ds_read_b128 conflicts 16-way -> 2-way.
__global__ __launch_bounds__(256, 8) void k3_htwo(
    const float* __restrict__ h_two,
    const float* __restrict__ b2,
    const ushort* __restrict__ wt,
    float* __restrict__ g2acc,
    float* __restrict__ out_h2)
{
  __shared__ __align__(16) ushort At[64*128];   // bf16, rows r=di*4+dj, swizzled
  const int tid = threadIdx.x;
  const int w = tid>>6, lane = tid&63;
  const int lq = lane>>4, lr = lane&15;
  const int bi = blockIdx.x & 31, bj = blockIdx.x >> 5;
  const int i0 = bi*16, j0 = bj*4;
  const int spin = bi>>4;

  // stage 16 i x 4 j x 128 k: coalesced f32 read -> bf16 -> swizzled LDS write
  #pragma unroll
  for(int rep=0;rep<8;rep++){
    const int e = rep*1024 + tid*4;            // flat elem: e = r*128 + k
    const int di = e>>9, c = e&511;
    const float4 v = *(const float4*)(h_two + ((size_t)(i0+di)*NN + j0)*PAIR + c);
    ushort4 pk; pk.x=f2b(v.x); pk.y=f2b(v.y); pk.z=f2b(v.z); pk.w=f2b(v.w);
    const int r = e>>7;
    *(ushort4*)(&At[e ^ ((r&7)<<3)]) = pk;
  }

  // W2^T fragments + bias from global (L2-hot; needed only after barrier)
  bf16x8 af[2][4];
  #pragma unroll
  for(int nt=0;nt<2;nt++){
    const int n = w*32 + nt*16 + lr;
    #pragma unroll
    for(int kk=0;kk<4;kk++)
      af[nt][kk] = *(const bf16x8*)(wt + n*128 + kk*32 + lq*8);
  }
  f32x4 bias[2];
  #pragma unroll
  for(int nt=0;nt<2;nt++){
    const float4 bv = *(const float4*)(b2 + w*32 + nt*16 + lq*4);
    bias[nt] = (f32x4){bv.x, bv.y, bv.z, bv.w};
  }
  __syncthreads();

  // g2 column sums over the 16 i's (bf16-sourced; error << tolerance)
  {
    const int dj = w, pp = lane;
    const uint* a32 = (const uint*)At;
    float s0=0.f, s1=0.f;
    #pragma unroll
    for(int di=0;di<16;di++){
      const int r = di*4+dj;
      uint u = a32[(r*64 + pp) ^ ((r&7)<<2)];
      s0 += b2f_lo(u); s1 += b2f_hi(u);
    }
    float* dst = g2acc + ((size_t)spin*NN + (j0+dj))*PAIR + pp*2;
    atomicAdd(dst, s0); atomicAdd(dst+1, s1);
  }

  // GEMM: D[n][m], A-op = W2^T frags (regs), B-op = At frags (swizzled LDS)
  f32x4 acc[4][2];
  #pragma unroll
  for(int mt=0;mt<4;mt++){
    acc[mt][0] = bias[0];
    acc[mt][1] = bias[1];
  }
  #pragma unroll
  for(int kk=0;kk<4;kk++){
    bf16x8 bfr[4];
    #pragma unroll
    for(int mt=0;mt<4;mt++){
      const int m = mt*16 + lr;                 // (m&7) == (lr&7)
      const int e = m*128 + kk*32 + lq*8;
      bfr[mt] = *(const bf16x8*)(&At[e ^ ((lr&7)<<3)]);
    }
    #pragma unroll
    for(int mt=0;mt<4;mt++){
      acc[mt][0] = __builtin_amdgcn_mfma_f32_16x16x32_bf16(af[0][kk], bfr[mt], acc[mt][0], 0,0,0);
      acc[mt][1] = __builtin_amdgcn_mfma_f32_16x16x32_bf16(af[1][kk], bfr[mt], acc[mt][1], 0,0,0);
    }
  }

  // epilogue: tanh*gain + residual (f32 re-read, L1/L2 hot), regular stores
  #pragma unroll
  for(int mt=0;mt<4;mt++){
    const int m = mt*16 + lr;
    const size_t base = ((size_t)(i0 + (m>>2))*NN + (j0 + (m&3)))*PAIR;
    #pragma unroll
    for(int nt=0;nt<2;nt++){
      const int nb = w*32 + nt*16 + lq*4;
      const float4 rr = *(const float4*)(h_two + base + nb);
      f32x4 o;
      o[0] = (rr.x + GAINv*tanh_fast(acc[mt][nt][0]))*RS2;
      o[1] = (rr.y + GAINv*tanh_fast(acc[mt][nt][1]))*RS2;
      o[2] = (rr.z + GAINv*tanh_fast(acc[mt][nt][2]))*RS2;
      o[3] = (rr.w + GAINv*tanh_fast(acc[mt][nt][3]))*RS2;
      *(f32x4*)(out_h2 + base + nb) = o;
    }
  }
}

// ---------------- k4: h_one path — 1 row/block (512 blocks = 2/CU) ----------------
__global__ __launch_bounds__(256) void k4_hone(
    const float* __restrict__ h_one,
    const float* __restrict__ w1,
    const float* __restrict__ b1,
    const float* __restrict__ g2acc,
    const float* __restrict__ gtermpart,
    float* __restrict__ out_h1)
{
  __shared__ float onein[512];
  const int n   = threadIdx.x;
  const int row = blockIdx.x;
  onein[n] = h_one[(size_t)row*SINGLE + n];
  {
    int sp = n>>7, p = n&127;
    onein[256+n] = g2acc[((size_t)sp*NN + row)*PAIR + p] * (1.f/256.f);
  }
  float gt = 0.f;
  #pragma unroll
  for(int bb=0;bb<8;bb++) gt += gtermpart[bb*256+n];
  __syncthreads();
  float a = 0.f;
  for(int f=0; f<512; f++)
    a += onein[f] * w1[(size_t)f*SINGLE + n];
  float x = (a + b1[n] + gt) * RS2;
  out_h1[(size_t)row*SINGLE + n] = (onein[n] + GAINv*tanh_fast(x)) * RS2;
}

extern "C" void kernel_launch(void* const* d_in, const int* in_sizes, int n_in,
                              void* d_out, int out_size, void* d_ws, size_t ws_size,
                              hipStream_t stream)
{
  const float* h_one = (const float*)d_in[0];
  const float* h_two = (const float*)d_in[1];
  const float* W1    = (const float*)d_in[2];
  const float* b1    = (const float*)d_in[3];
  const float* Wg    = (const float*)d_in[4];
  const float* W2    = (const float*)d_in[5];
  const float* b2    = (const float*)d_in[6];

  float* wsf       = (float*)d_ws;
  float* g2acc     = wsf;                        // [2][512][128] f32 sums (atomic)
  ushort* wt       = (ushort*)(wsf + 131072);    // W2^T bf16 [n][k], linear
  float* g1part    = wsf + 139264;               // [8][256] spin partial sums
  float* gtermpart = wsf + 141312;               // [8][256] gterm partials

  float* out_h1 = (float*)d_out;
  float* out_h2 = out_h1 + 131072;

  k1_prep <<<24,   256, 0, stream>>>(h_one, W2, g1part, wt, g2acc);
  k2_gterm<<<8,    256, 0, stream>>>(g1part, Wg, gtermpart);
  k3_htwo <<<4096, 256, 0, stream>>>(h_two, b2, wt, g2acc, out_h2);
  k4_hone <<<512,  256, 0, stream>>>(h_one, W1, b1, g2acc, gtermpart, out_h1);
}

// Round 6
// 286.791 us; speedup vs baseline: 1.2020x; 1.1665x over previous
//
#include <hip/hip_runtime.h>
#include <stdint.h>

#define NN 512
#define PAIR 128
#define SINGLE 256

#define GAINv 1.5927812698663017f
#define RS2 0.70710678118654752f

typedef unsigned int uint;
typedef unsigned short ushort;
typedef short bf16x8 __attribute__((ext_vector_type(8)));
typedef float f32x4 __attribute__((ext_vector_type(4)));

__device__ __forceinline__ ushort f2b(float f){
  union{float f;uint i;}v; v.f=f;
  uint x=v.i;
  return (ushort)((x + 0x7FFFu + ((x>>16)&1u))>>16);  // RNE, finite inputs only
}
__device__ __forceinline__ float b2f_lo(uint u){ union{uint i;float f;}v; v.i=u<<16; return v.f; }
__device__ __forceinline__ float b2f_hi(uint u){ union{uint i;float f;}v; v.i=u&0xFFFF0000u; return v.f; }
__device__ __forceinline__ float tanh_fast(float x){
  float xc = fminf(fmaxf(x,-8.f),8.f);
  float e = __expf(2.f*xc);
  return (e-1.f)*__builtin_amdgcn_rcpf(e+1.f);
}

// ---------------- k1: g1 spin-partials + W2^T->bf16 + zero g2acc ------------------
__global__ __launch_bounds__(256) void k1_prep(const float* __restrict__ h_one,
                                               const float* __restrict__ w2,
                                               float* __restrict__ g1part,
                                               ushort* __restrict__ wt,
                                               float* __restrict__ g2acc)
{
  const int b = blockIdx.x, t = threadIdx.x;
  if(b < 8){
    const int rb = b*64;
    float s = 0.f;
    for(int i=0;i<64;i++) s += h_one[(size_t)(rb+i)*SINGLE + t];
    g1part[b*SINGLE + t] = s;                    // blocks 0..3 spin0, 4..7 spin1
  } else if(b < 16){
    const int bb = b-8;                          // 16 rows of W2 each
    for(int e=t; e<16*128; e+=256){
      int kl = e>>7, n = e&127;
      int k = bb*16 + kl;
      wt[n*128 + k] = f2b(w2[(size_t)k*128 + n]);  // wt[n][k] = bf16(W2[k][n]), linear
    }
  } else {
    // zero g2acc: 131072 floats = 32768 f32x4, 8 blocks
    f32x4 z = (f32x4){0.f,0.f,0.f,0.f};
    f32x4* dst = (f32x4*)g2acc + (size_t)(b-16)*4096;
    for(int q=t; q<4096; q+=256) dst[q] = z;
  }
}

// ---------------- k2: gterm partials (plain stores, no atomics) -------------------
__global__ __launch_bounds__(256) void k2_gterm(const float* __restrict__ g1part,
                                                const float* __restrict__ wg,
                                                float* __restrict__ gtermpart)
{
  __shared__ float g1m[512];
  const int t = threadIdx.x;
  g1m[t]     = (g1part[t]      + g1part[256+t]  + g1part[512+t]  + g1part[768+t])  * (1.f/256.f);
  g1m[t+256] = (g1part[1024+t] + g1part[1280+t] + g1part[1536+t] + g1part[1792+t]) * (1.f/256.f);
  __syncthreads();
  const int fb = blockIdx.x*64;
  float s = 0.f;
  for(int f=fb; f<fb+64; f++)
    s += g1m[f]*wg[(size_t)f*SINGLE + t];
  gtermpart[blockIdx.x*SINGLE + t] = s;
}

// ---------------- k3: h_two fused GEMM, 16i x 4j tile ------------------------------
// R3 stage/g2/GEMM; NEW epilogue: residual kept in registers (L[8]), tanh-term
// staged through LDS (reusing At, f32, 2 halves, swizzled) so global stores are
// fully coalesced 16B/lane streams and there are ZERO global re-reads.
__global__ __launch_bounds__(256, 4) void k3_htwo(
    const float* __restrict__ h_two,
    const float* __restrict__ b2,
    const ushort* __restrict__ wt,
    float* __restrict__ g2acc,
    float* __restrict__ out_h2)
{
  __shared__ __align__(16) ushort At[64*128];   // 16KB: bf16 operands, then f32 out-stage
  float* LDSf = (float*)At;                     // 32 rows x 128 f32 per half
  const int tid = threadIdx.x;
  const int w = tid>>6, lane = tid&63;
  const int lq = lane>>4, lr = lane&15;
  const int bi = blockIdx.x & 31, bj = blockIdx.x >> 5;
  const int i0 = bi*16, j0 = bj*4;
  const int spin = bi>>4;

  // stage 16 i x 4 j x 128 k: coalesced f32 read -> bf16 -> swizzled LDS write.
  // KEEP the f32 values in registers for the residual.
  float4 L[8];
  #pragma unroll
  for(int rep=0;rep<8;rep++){
    const int e = rep*1024 + tid*4;            // flat elem: e = r*128 + k
    const int di = e>>9, c = e&511;
    L[rep] = *(const float4*)(h_two + ((size_t)(i0+di)*NN + j0)*PAIR + c);
  }
  #pragma unroll
  for(int rep=0;rep<8;rep++){
    const int e = rep*1024 + tid*4;
    const int r = e>>7;
    ushort4 pk; pk.x=f2b(L[rep].x); pk.y=f2b(L[rep].y); pk.z=f2b(L[rep].z); pk.w=f2b(L[rep].w);
    *(ushort4*)(&At[e ^ ((r&7)<<3)]) = pk;
  }

  // W2^T fragments + bias from global (L2-hot; needed only after barrier)
  bf16x8 af[2][4];
  #pragma unroll
  for(int nt=0;nt<2;nt++){
    const int n = w*32 + nt*16 + lr;
    #pragma unroll
    for(int kk=0;kk<4;kk++)
      af[nt][kk] = *(const bf16x8*)(wt + n*128 + kk*32 + lq*8);
  }
  f32x4 bias[2];
  #pragma unroll
  for(int nt=0;nt<2;nt++){
    const float4 bv = *(const float4*)(b2 + w*32 + nt*16 + lq*4);
    bias[nt] = (f32x4){bv.x, bv.y, bv.z, bv.w};
  }
  __syncthreads();

  // g2 column sums over the 16 i's (bf16-sourced; error << tolerance)
  {
    const int dj = w, pp = lane;
    const uint* a32 = (const uint*)At;
    float s0=0.f, s1=0.f;
    #pragma unroll
    for(int di=0;di<16;di++){
      const int r = di*4+dj;
      uint u = a32[(r*64 + pp) ^ ((r&7)<<2)];
      s0 += b2f_lo(u); s1 += b2f_hi(u);
    }
    float* dst = g2acc + ((size_t)spin*NN + (j0+dj))*PAIR + pp*2;
    atomicAdd(dst, s0); atomicAdd(dst+1, s1);
  }

  // GEMM: D[n][m], A-op = W2^T frags (regs), B-op = At frags (swizzled LDS)
  f32x4 acc[4][2];
  #pragma unroll
  for(int mt=0;mt<4;mt++){
    acc[mt][0] = bias[0];
    acc[mt][1] = bias[1];
  }
  #pragma unroll
  for(int kk=0;kk<4;kk++){
    bf16x8 bfr[4];
    #pragma unroll
    for(int mt=0;mt<4;mt++){
      const int m = mt*16 + lr;                 // (m&7) == (lr&7)
      const int e = m*128 + kk*32 + lq*8;
      bfr[mt] = *(const bf16x8*)(&At[e ^ ((lr&7)<<3)]);
    }
    #pragma unroll
    for(int mt=0;mt<4;mt++){
      acc[mt][0] = __builtin_amdgcn_mfma_f32_16x16x32_bf16(af[0][kk], bfr[mt], acc[mt][0], 0,0,0);
      acc[mt][1] = __builtin_amdgcn_mfma_f32_16x16x32_bf16(af[1][kk], bfr[mt], acc[mt][1], 0,0,0);
    }
  }
  __syncthreads();   // all At (bf16) reads done; LDS now reusable as f32 out-stage

  // epilogue: per half (rows 0-31, 32-63): stage GAIN*tanh(acc) into LDS (f32,
  // swizzled), then read back at the STAGE flat mapping, add register residual,
  // and store fully coalesced.
  #pragma unroll
  for(int h=0;h<2;h++){
    #pragma unroll
    for(int mtl=0;mtl<2;mtl++){
      const int mt = 2*h + mtl;
      const int rloc = (mt*16 + lr) & 31;       // (rloc&7) == (lr&7)
      #pragma unroll
      for(int nt=0;nt<2;nt++){
        const int col = w*32 + nt*16 + lq*4;
        f32x4 tv;
        tv[0] = GAINv*tanh_fast(acc[mt][nt][0]);
        tv[1] = GAINv*tanh_fast(acc[mt][nt][1]);
        tv[2] = GAINv*tanh_fast(acc[mt][nt][2]);
        tv[3] = GAINv*tanh_fast(acc[mt][nt][3]);
        *(f32x4*)(&LDSf[rloc*128 + (col ^ ((lr&7)<<2))]) = tv;
      }
    }
    __syncthreads();
    #pragma unroll
    for(int rep=0;rep<4;rep++){
      const int repg = h*4 + rep;
      const int e = repg*1024 + tid*4;          // global flat (matches stage load)
      const int eloc = e & 4095;
      const int r = eloc>>7, c = eloc&127;
      const f32x4 tv = *(const f32x4*)(&LDSf[r*128 + (c ^ ((r&7)<<2))]);
      const int di = e>>9, c511 = e&511;
      f32x4 o;
      o[0] = (L[repg].x + tv[0])*RS2;
      o[1] = (L[repg].y + tv[1])*RS2;
      o[2] = (L[repg].z + tv[2])*RS2;
      o[3] = (L[repg].w + tv[3])*RS2;
      *(f32x4*)(out_h2 + ((size_t)(i0+di)*NN + j0)*PAIR + c511) = o;
    }
    if(h==0) __syncthreads();
  }
}

// ---------------- k4: h_one path — 1 row/block (512 blocks = 2/CU) ----------------
__global__ __launch_bounds__(256) void k4_hone(
    const float* __restrict__ h_one,
    const float* __restrict__ w1,
    const float* __restrict__ b1,
    const float* __restrict__ g2acc,
    const float* __restrict__ gtermpart,
    float* __restrict__ out_h1)
{
  __shared__ float onein[512];
  const int n   = threadIdx.x;
  const int row = blockIdx.x;
  onein[n] = h_one[(size_t)row*SINGLE + n];
  {
    int sp = n>>7, p = n&127;
    onein[256+n] = g2acc[((size_t)sp*NN + row)*PAIR + p] * (1.f/256.f);
  }
  float gt = 0.f;
  #pragma unroll
  for(int bb=0;bb<8;bb++) gt += gtermpart[bb*256+n];
  __syncthreads();
  float a = 0.f;
  for(int f=0; f<512; f++)
    a += onein[f] * w1[(size_t)f*SINGLE + n];
  float x = (a + b1[n] + gt) * RS2;
  out_h1[(size_t)row*SINGLE + n] = (onein[n] + GAINv*tanh_fast(x)) * RS2;
}

extern "C" void kernel_launch(void* const* d_in, const int* in_sizes, int n_in,
                              void* d_out, int out_size, void* d_ws, size_t ws_size,
                              hipStream_t stream)
{
  const float* h_one = (const float*)d_in[0];
  const float* h_two = (const float*)d_in[1];
  const float* W1    = (const float*)d_in[2];
  const float* b1    = (const float*)d_in[3];
  const float* Wg    = (const float*)d_in[4];
  const float* W2    = (const float*)d_in[5];
  const float* b2    = (const float*)d_in[6];

  float* wsf       = (float*)d_ws;
  float* g2acc     = wsf;                        // [2][512][128] f32 sums (atomic)
  ushort* wt       = (ushort*)(wsf + 131072);    // W2^T bf16 [n][k], linear
  float* g1part    = wsf + 139264;               // [8][256] spin partial sums
  float* gtermpart = wsf + 141312;               // [8][256] gterm partials

  float* out_h1 = (float*)d_out;
  float* out_h2 = out_h1 + 131072;

  k1_prep <<<24,   256, 0, stream>>>(h_one, W2, g1part, wt, g2acc);
  k2_gterm<<<8,    256, 0, stream>>>(g1part, Wg, gtermpart);
  k3_htwo <<<4096, 256, 0, stream>>>(h_two, b2, wt, g2acc, out_h2);
  k4_hone <<<512,  256, 0, stream>>>(h_one, W1, b1, g2acc, gtermpart, out_h1);
}